// Round 17
// baseline (146.317 us; speedup 1.0000x reference)
//
#include <hip/hip_runtime.h>
#include <hip/hip_bf16.h>
#include <math.h>

// Geometry
#define WPD 266   // padded H=W
#define HO2 260   // h2 (after conv1+conv2)
#define HO3 258   // h3 (virtual; lives only in LDS)
#define HO4 256

typedef __attribute__((ext_vector_type(8))) short short8_t;
typedef __attribute__((ext_vector_type(4))) short short4_t;
typedef __attribute__((ext_vector_type(4))) float float4_t;

__device__ inline void gld16(const void* g, void* l) {
  __builtin_amdgcn_global_load_lds(
      (const __attribute__((address_space(1))) void*)g,
      (__attribute__((address_space(3))) void*)l, 16, 0, 0);
}

// ---------------- pad fill: xp = pad(x, 5, value=0.5) ----------------
__global__ void pad_fill_kernel(const float* __restrict__ x, float* __restrict__ xp,
                                int bBase, int gc) {
  size_t total = (size_t)gc * WPD * WPD;
  for (size_t idx = (size_t)blockIdx.x * blockDim.x + threadIdx.x; idx < total;
       idx += (size_t)gridDim.x * blockDim.x) {
    size_t zb = idx / (WPD * WPD);
    int rem = (int)(idx % (WPD * WPD));
    int y = rem / WPD, xx = rem % WPD;
    float v = 0.5f;
    if (y >= 5 && y < 261 && xx >= 5 && xx < 261)
      v = x[((size_t)(bBase + zb) * 256 + (y - 5)) * 256 + (xx - 5)];
    xp[idx] = v;
  }
}

// ---------------- border extrapolation (sequential rings i=5..1) ----------------
__global__ void extrap_kernel(float* __restrict__ xp) {
  const int W = WPD, H = WPD;
  float* p = xp + (size_t)blockIdx.x * W * W;
  for (int i = 5; i >= 1; --i) {
    int ip = i + 1, im = i - 1;
    int L = W - 2 * ip;
    for (int t = threadIdx.x; t < 4 * L; t += blockDim.x) {
      int e = t / L, j = t % L;
      float a;
      if (e == 0) {
        a = (p[i * W + i + j] + p[i * W + i + j + 1] + p[i * W + i + j + 2]) / 3.0f;
        p[im * W + ip + j] = a > 0.3f ? 1.0f : a;
      } else if (e == 1) {
        const float* r = p + (H - ip) * W;
        a = (r[i + j] + r[i + j + 1] + r[i + j + 2]) / 3.0f;
        p[(H - i) * W + ip + j] = a > 0.3f ? 1.0f : a;
      } else if (e == 2) {
        a = (p[(i + j) * W + i] + p[(i + j + 1) * W + i] + p[(i + j + 2) * W + i]) / 3.0f;
        p[(ip + j) * W + im] = a > 0.3f ? 1.0f : a;
      } else {
        a = (p[(i + j) * W + (W - ip)] + p[(i + j + 1) * W + (W - ip)] +
             p[(i + j + 2) * W + (W - ip)]) / 3.0f;
        p[(ip + j) * W + (W - i)] = a > 0.3f ? 1.0f : a;
      }
    }
    __syncthreads();
    if (threadIdx.x < 4) {
      int c = threadIdx.x;
      int cx, cy, nx, ny;
      if (c == 0)      { cx = im;    cy = im;    nx = 1;  ny = 1;  }
      else if (c == 1) { cx = W - i; cy = im;    nx = -1; ny = 1;  }
      else if (c == 2) { cx = W - i; cy = H - i; nx = -1; ny = -1; }
      else             { cx = im;    cy = H - i; nx = 1;  ny = -1; }
      int cxp = cx + nx, cyp = cy + ny;
      p[cy * W + cxp] = (p[cyp * W + cxp] + p[cy * W + cx + 2 * nx]) * 0.5f;
      p[cyp * W + cx] = (p[cyp * W + cxp] + p[(cy + 2 * ny) * W + cx]) * 0.5f;
      p[cy * W + cx]  = (p[cy * W + cxp] + p[cyp * W + cx]) * 0.5f;
    }
    __syncthreads();
  }
}

// ---------------- merged weight repack (w1 | w2 | w3 | w4 in one dispatch) ----
__device__ inline void repack33(const float* W, __hip_bfloat16* Wr, int idx,
                                int CIN, int COUT) {
  int NC = CIN / 32, NF = COUT / 16;
  int j = idx & 7, l = (idx >> 3) & 63;
  int rest = idx >> 9;
  int n = rest % NF; rest /= NF;
  int c = rest % NC; int t = rest / NC;
  int oc = n * 16 + (l & 15);
  int ic = c * 32 + (l >> 4) * 8 + j;
  Wr[idx] = __float2bfloat16(W[((size_t)oc * CIN + ic) * 9 + t]);
}

__global__ void repack_all(const float* __restrict__ W1, const float* __restrict__ W2,
                           const float* __restrict__ W3, const float* __restrict__ W4,
                           __hip_bfloat16* __restrict__ wr) {
  int idx = blockIdx.x * blockDim.x + threadIdx.x;
  if (idx < 2048) {
    int j = idx & 7, l = (idx >> 3) & 63, n = idx >> 9;
    int oc = n * 16 + (l & 15);
    int tap = (l >> 4) * 8 + j;
    wr[idx] = __float2bfloat16(tap < 25 ? W1[oc * 25 + tap] : 0.0f);
  } else if (idx < 20480) {
    repack33(W2, wr + 2048, idx - 2048, 64, 32);
  } else if (idx < 29696) {
    repack33(W3, wr + 20480, idx - 20480, 32, 32);
  } else if (idx < 34304) {
    repack33(W4, wr + 29696, idx - 29696, 32, 16);
  }
}

// involutive bank-spreading swizzle of the 4-chunk index by tile-local x
__device__ inline int swz4(int x) { return (x & 3) ^ ((x >> 2) & 3); }

// ---------------- fused conv1(5x5,1->64)+conv2(3x3,64->32): h1 stays in LDS ----
__global__ __launch_bounds__(256, 2)
void conv12_mfma(
    const float* __restrict__ xp, __hip_bfloat16* __restrict__ h2,
    const __hip_bfloat16* __restrict__ w1r, const float* __restrict__ b1,
    const __hip_bfloat16* __restrict__ w2r, const float* __restrict__ b2) {
  const int HIN = WPD;        // xp 266
  const int HO = HO2;         // 260
  const int zb = blockIdx.z;
  const float* p = xp + (size_t)zb * HIN * HIN;
  const int x0 = blockIdx.x * 16, y0 = blockIdx.y * 16;
  const int lane = threadIdx.x & 63;
  const int wave = threadIdx.x >> 6;
  const int lx = lane & 15, kg = lane >> 4;

  __shared__ short lds1[26 * 22];   // rows 0..21 xp data, 22..25 zeros
  __shared__ char lds2[18 * 2304];  // 18x18 x 64ch bf16, CBC=8 chunk-swizzled

  // ---- stage xp patch (f32 -> bf16), zero pad rows ----
  for (int idx = threadIdx.x; idx < 26 * 22; idx += 256) {
    int r = idx / 22, c = idx % 22;
    short v = 0;
    if (r < 22) {
      int yy = min(y0 + r, HIN - 1), xx = min(x0 + c, HIN - 1);
      __hip_bfloat16 h = __float2bfloat16(p[yy * HIN + xx]);
      v = *reinterpret_cast<short*>(&h);
    }
    lds1[idx] = v;
  }

  // conv1 tap offsets (lane-dependent)
  int toff[8]; bool tvalid[8];
#pragma unroll
  for (int j = 0; j < 8; ++j) {
    int tap = kg * 8 + j;
    int ky = tap / 5, kx = tap - ky * 5;
    tvalid[j] = tap < 25;
    toff[j] = ky * 22 + kx;
  }
  // conv2 A-fragment byte bases: pixel x = lx+kx, chunk c = cg*4+kg, slot = c^(x&7)
  int abase[3][2];
#pragma unroll
  for (int kx = 0; kx < 3; ++kx) {
#pragma unroll
    for (int cg = 0; cg < 2; ++cg) {
      int x = lx + kx;
      int c = cg * 4 + kg;
      int slot = c ^ (x & 7);
      abase[kx][cg] = (x * 8 + slot) * 16 + wave * 4 * 2304;
    }
  }

  // conv1 store addresses: pixel = mi*64+wave*16+lx; oc-group n: cb = n*2+(kg>>1)
  int saddr[6][4];
  bool svalid[6];
#pragma unroll
  for (int mi = 0; mi < 6; ++mi) {
    int pixel = mi * 64 + wave * 16 + lx;
    svalid[mi] = pixel < 324;
    int pc = pixel < 324 ? pixel : 323;
    int y2 = pc / 18, x2 = pc - y2 * 18;
#pragma unroll
    for (int n = 0; n < 4; ++n) {
      int cb = n * 2 + (kg >> 1);
      int slot = cb ^ (x2 & 7);
      saddr[mi][n] = y2 * 2304 + (x2 * 8 + slot) * 16 + (kg & 1) * 8;
    }
  }

  __syncthreads();  // lds1 ready

  // ---- hoist conv1 A-fragments: 6 x short8 = 24 VGPR ----
  short8_t Af[6];
#pragma unroll
  for (int mi = 0; mi < 6; ++mi) {
    int pp = mi * 64 + wave * 16 + lx;
    pp = pp < 324 ? pp : 323;
    int y1 = pp / 18, x1 = pp - y1 * 18;
    int bs = y1 * 22 + x1;
#pragma unroll
    for (int j = 0; j < 8; ++j)
      Af[mi][j] = lds1[tvalid[j] ? bs + toff[j] : 484 + lx];
  }

  // ---- conv1: all 64 oc in one pass, swapped-operand MFMA + b64 stores ----
  {
    short8_t B1[4];
    float4_t binit[4];
#pragma unroll
    for (int n = 0; n < 4; ++n) {
      B1[n] = *reinterpret_cast<const short8_t*>(w1r + (size_t)(n * 64 + lane) * 8);
      binit[n] = *reinterpret_cast<const float4_t*>(b1 + n * 16 + kg * 4);
    }
#pragma unroll
    for (int mi = 0; mi < 6; ++mi) {
      if (mi * 64 + wave * 16 < 324) {   // wave-uniform tail skip
        float4_t a[4];
#pragma unroll
        for (int n = 0; n < 4; ++n) {
          a[n] = binit[n];
          a[n] = __builtin_amdgcn_mfma_f32_16x16x32_bf16(B1[n], Af[mi], a[n], 0, 0, 0);
        }
        if (svalid[mi]) {
#pragma unroll
          for (int n = 0; n < 4; ++n) {
            short4_t s;
#pragma unroll
            for (int r = 0; r < 4; ++r) {
              float v = a[n][r] > 0.0f ? a[n][r] : 0.0f;
              __hip_bfloat16 h = __float2bfloat16(v);
              s[r] = *reinterpret_cast<short*>(&h);
            }
            *reinterpret_cast<short4_t*>(lds2 + saddr[mi][n]) = s;
          }
        }
      }
    }
  }
  __syncthreads();  // lds2 (h1, all 64 ch) ready

  // ---- conv2: kx-major with A-row register cache (6 rows per (kx,cg)) ----
  float4_t acc2[4][2];
  {
    float4_t binit2[2];
#pragma unroll
    for (int n = 0; n < 2; ++n)
      binit2[n] = *reinterpret_cast<const float4_t*>(b2 + n * 16 + kg * 4);
#pragma unroll
    for (int m = 0; m < 4; ++m)
#pragma unroll
      for (int n = 0; n < 2; ++n) acc2[m][n] = binit2[n];
  }

#pragma unroll
  for (int kx = 0; kx < 3; ++kx) {
#pragma unroll
    for (int cg = 0; cg < 2; ++cg) {
      short8_t Ar[6];
#pragma unroll
      for (int rr = 0; rr < 6; ++rr)
        Ar[rr] = *reinterpret_cast<const short8_t*>(
            lds2 + abase[kx][cg] + rr * 2304);
#pragma unroll
      for (int ky = 0; ky < 3; ++ky) {
        const int t = ky * 3 + kx;
        short8_t B2[2];
#pragma unroll
        for (int n = 0; n < 2; ++n)
          B2[n] = *reinterpret_cast<const short8_t*>(
              w2r + (size_t)(((t * 2 + cg) * 2 + n) * 64 + lane) * 8);
#pragma unroll
        for (int m = 0; m < 4; ++m)
#pragma unroll
          for (int n = 0; n < 2; ++n)
            acc2[m][n] = __builtin_amdgcn_mfma_f32_16x16x32_bf16(
                B2[n], Ar[m + ky], acc2[m][n], 0, 0, 0);
      }
    }
  }

  // ---- epilogue (swapped layout): pixel = x0+lx, oc = n*16 + kg*4 + r ----
  __hip_bfloat16* op = h2 + (size_t)zb * HO * HO * 32;
  int xx = x0 + lx;
  if (xx < HO) {
#pragma unroll
    for (int m = 0; m < 4; ++m) {
      int yy = y0 + wave * 4 + m;
      if (yy < HO) {
#pragma unroll
        for (int n = 0; n < 2; ++n) {
          short4_t s;
#pragma unroll
          for (int r = 0; r < 4; ++r) {
            float v = acc2[m][n][r];
            v = v > 0.0f ? v : 0.0f;
            __hip_bfloat16 h = __float2bfloat16(v);
            s[r] = *reinterpret_cast<short*>(&h);
          }
          *reinterpret_cast<short4_t*>(op + ((size_t)yy * HO + xx) * 32 + n * 16 + kg * 4) = s;
        }
      }
    }
  }
}

// ---------------- fused conv3(3x3,32->32)+conv4(3x3,32->16)+sigmoid+shuffle ----
// conv3 restructured t-OUTER with persistent a3[6][2] accumulators:
// B-fragment global loads 108 -> 18 per wave (was re-issued per mi because
// CSE across the mi-unroll needs 72 regs the allocator didn't have).
// Per-accumulator tap order unchanged (t = 0..8) -> bit-identical.
__global__ __launch_bounds__(256, 2)
void conv34_mfma(
    const __hip_bfloat16* __restrict__ h2, float* __restrict__ out,
    const __hip_bfloat16* __restrict__ w3r, const float* __restrict__ b3,
    const __hip_bfloat16* __restrict__ w4r, const float* __restrict__ b4,
    int bBase) {
  const int HIN = HO2;   // 260
  const int zb = blockIdx.z;
  const __hip_bfloat16* ip = h2 + (size_t)zb * HIN * HIN * 32;
  const int x0 = blockIdx.x * 16, y0 = blockIdx.y * 16;
  const int lane = threadIdx.x & 63;
  const int wave = threadIdx.x >> 6;
  const int lx = lane & 15, kg = lane >> 4;

  constexpr int SLOTS = 20 * 20 * 4;            // 1600
  constexpr int ITERS = (SLOTS + 255) / 256;    // 7
  __shared__ char lds1[ITERS * 256 * 16];       // 28672 B: 20x20x32 h2 tile
  __shared__ char lds2[18 * 1152];              // 20736 B: 18x18x32 h3 tile

  // ---- stage h2 tile (swizzled global source, linear LDS dest) ----
#pragma unroll
  for (int i = 0; i < ITERS; ++i) {
    int sbase = i * 256 + wave * 64;            // wave-uniform
    int slot = sbase + lane;
    slot = slot < SLOTS ? slot : SLOTS - 1;
    int pix = slot >> 2, scb = slot & 3;
    int y = pix / 20, x = pix - y * 20;
    int cb = scb ^ swz4(x);
    const __hip_bfloat16* src = ip + ((size_t)(y0 + y) * HIN + (x0 + x)) * 32 + cb * 8;
    gld16(src, lds1 + (size_t)sbase * 16);
  }

  // conv4 fragment byte bases (per kx) into lds2
  int abase4[3];
#pragma unroll
  for (int kx = 0; kx < 3; ++kx) {
    int x = lx + kx;
    int slot = kg ^ swz4(x);
    abase4[kx] = (x * 4 + slot) * 16 + wave * 4 * 1152;
  }

  // conv3 per-mi addresses (pixel-linearized over 18x18 h3 tile)
  int a3base[6];
  int s3[6][3];
  int saddr[6][2];
  bool svalid[6];
#pragma unroll
  for (int mi = 0; mi < 6; ++mi) {
    int pixel = mi * 64 + wave * 16 + lx;
    svalid[mi] = pixel < 324;
    int pc = pixel < 324 ? pixel : 323;
    int y1 = pc / 18, x1 = pc - y1 * 18;
    a3base[mi] = (y1 * 20 + x1) * 64;
#pragma unroll
    for (int kx = 0; kx < 3; ++kx) s3[mi][kx] = kg ^ swz4(x1 + kx);
#pragma unroll
    for (int n2 = 0; n2 < 2; ++n2) {
      int cb = n2 * 2 + (kg >> 1);
      int slot = cb ^ swz4(x1);
      saddr[mi][n2] = y1 * 1152 + (x1 * 4 + slot) * 16 + (kg & 1) * 8;
    }
  }

  float4_t binit3[2];
#pragma unroll
  for (int n2 = 0; n2 < 2; ++n2)
    binit3[n2] = *reinterpret_cast<const float4_t*>(b3 + n2 * 16 + kg * 4);

  __syncthreads();  // lds1 ready

  // ---- conv3: t-outer, persistent accumulators (18 B-loads total) ----
  float4_t a3[6][2];
#pragma unroll
  for (int mi = 0; mi < 6; ++mi) {
    a3[mi][0] = binit3[0];
    a3[mi][1] = binit3[1];
  }
#pragma unroll
  for (int t = 0; t < 9; ++t) {
    const int ky = t / 3, kx = t % 3;
    short8_t B30 = *reinterpret_cast<const short8_t*>(
        w3r + (size_t)((t * 2 + 0) * 64 + lane) * 8);
    short8_t B31 = *reinterpret_cast<const short8_t*>(
        w3r + (size_t)((t * 2 + 1) * 64 + lane) * 8);
#pragma unroll
    for (int mi = 0; mi < 6; ++mi) {
      if (mi * 64 + wave * 16 < 324) {          // wave-uniform tail skip
        short8_t A = *reinterpret_cast<const short8_t*>(
            lds1 + a3base[mi] + ky * 1280 + kx * 64 + s3[mi][kx] * 16);
        a3[mi][0] = __builtin_amdgcn_mfma_f32_16x16x32_bf16(B30, A, a3[mi][0], 0, 0, 0);
        a3[mi][1] = __builtin_amdgcn_mfma_f32_16x16x32_bf16(B31, A, a3[mi][1], 0, 0, 0);
      }
    }
  }
  // ---- store h3 into lds2 ----
#pragma unroll
  for (int mi = 0; mi < 6; ++mi) {
    if (svalid[mi]) {
      short4_t s0, s1;
#pragma unroll
      for (int r = 0; r < 4; ++r) {
        float v0 = a3[mi][0][r] > 0.0f ? a3[mi][0][r] : 0.0f;
        float v1 = a3[mi][1][r] > 0.0f ? a3[mi][1][r] : 0.0f;
        __hip_bfloat16 h0 = __float2bfloat16(v0);
        __hip_bfloat16 h1 = __float2bfloat16(v1);
        s0[r] = *reinterpret_cast<short*>(&h0);
        s1[r] = *reinterpret_cast<short*>(&h1);
      }
      *reinterpret_cast<short4_t*>(lds2 + saddr[mi][0]) = s0;
      *reinterpret_cast<short4_t*>(lds2 + saddr[mi][1]) = s1;
    }
  }
  __syncthreads();  // lds2 (h3) ready

  // ---- conv4: kx-major with A-row register cache (6 rows per kx) ----
  float4_t binit4 = *reinterpret_cast<const float4_t*>(b4 + kg * 4);
  float4_t acc[4];
#pragma unroll
  for (int m = 0; m < 4; ++m) acc[m] = binit4;

#pragma unroll
  for (int kx = 0; kx < 3; ++kx) {
    short8_t Ar[6];
#pragma unroll
    for (int rr = 0; rr < 6; ++rr)
      Ar[rr] = *reinterpret_cast<const short8_t*>(lds2 + abase4[kx] + rr * 1152);
#pragma unroll
    for (int ky = 0; ky < 3; ++ky) {
      const int t = ky * 3 + kx;
      short8_t B = *reinterpret_cast<const short8_t*>(w4r + (size_t)(t * 64 + lane) * 8);
#pragma unroll
      for (int m = 0; m < 4; ++m)
        acc[m] = __builtin_amdgcn_mfma_f32_16x16x32_bf16(B, Ar[m + ky], acc[m], 0, 0, 0);
    }
  }

  // ---- sigmoid + pixel_shuffle (swapped): pixel = x0+lx, oc = kg*4+r ----
  float* ob = out + (size_t)(bBase + zb) * 1024 * 1024;
  int xx = x0 + lx;
#pragma unroll
  for (int m = 0; m < 4; ++m) {
    int yy = y0 + wave * 4 + m;
    float4_t v;
#pragma unroll
    for (int r = 0; r < 4; ++r) v[r] = 1.0f / (1.0f + expf(-acc[m][r]));
    *reinterpret_cast<float4_t*>(ob + (size_t)(yy * 4 + kg) * 1024 + xx * 4) = v;
  }
}

extern "C" void kernel_launch(void* const* d_in, const int* in_sizes, int n_in,
                              void* d_out, int out_size, void* d_ws, size_t ws_size,
                              hipStream_t stream) {
  const float* x  = (const float*)d_in[0];
  const float* W1 = (const float*)d_in[1];
  const float* b1 = (const float*)d_in[2];
  const float* W2 = (const float*)d_in[3];
  const float* b2 = (const float*)d_in[4];
  const float* W3 = (const float*)d_in[5];
  const float* b3 = (const float*)d_in[6];
  const float* W4 = (const float*)d_in[7];
  const float* b4 = (const float*)d_in[8];
  float* out = (float*)d_out;

  __hip_bfloat16* wr = (__hip_bfloat16*)d_ws;
  __hip_bfloat16* wr1 = wr;               // 2048 elems
  __hip_bfloat16* wr2 = wr + 2048;        // 18432
  __hip_bfloat16* wr3 = wr + 20480;       // 9216
  __hip_bfloat16* wr4 = wr + 29696;       // 4608 (total 34304)
  char* base = (char*)d_ws + 131072;

  const size_t xp_sz = (size_t)WPD * WPD * sizeof(float);
  const size_t h2_sz = (size_t)HO2 * HO2 * 32 * sizeof(__hip_bfloat16);
  const size_t per_b = xp_sz + h2_sz;     // ~4.6 MB/batch

  int g = (int)((ws_size - 131072) / per_b);
  if (g > 16) g = 16;
  if (g < 1) g = 1;

  float* xp = (float*)base;
  __hip_bfloat16* h2 = (__hip_bfloat16*)(base + (size_t)g * xp_sz);

  repack_all<<<134, 256, 0, stream>>>(W1, W2, W3, W4, wr);

  for (int bBase = 0; bBase < 16; bBase += g) {
    int gc = min(g, 16 - bBase);
    size_t tot = (size_t)gc * WPD * WPD;
    int fillBlocks = (int)min((tot + 255) / 256, (size_t)2048);
    pad_fill_kernel<<<fillBlocks, 256, 0, stream>>>(x, xp, bBase, gc);
    extrap_kernel<<<gc, 256, 0, stream>>>(xp);
    conv12_mfma<<<dim3(17, 17, gc), 256, 0, stream>>>(xp, h2, wr1, b1, wr2, b2);
    conv34_mfma<<<dim3(16, 16, gc), 256, 0, stream>>>(h2, out, wr3, b3, wr4, b4, bBase);
  }
}

// Round 18
// 140.424 us; speedup vs baseline: 1.0420x; 1.0420x over previous
//
#include <hip/hip_runtime.h>
#include <hip/hip_bf16.h>
#include <math.h>

// Geometry
#define WPD 266   // padded H=W
#define HO2 260   // h2 (after conv1+conv2)
#define HO3 258   // h3 (virtual; lives only in LDS)
#define HO4 256

typedef __attribute__((ext_vector_type(8))) short short8_t;
typedef __attribute__((ext_vector_type(4))) short short4_t;
typedef __attribute__((ext_vector_type(4))) float float4_t;

__device__ inline void gld16(const void* g, void* l) {
  __builtin_amdgcn_global_load_lds(
      (const __attribute__((address_space(1))) void*)g,
      (__attribute__((address_space(3))) void*)l, 16, 0, 0);
}

// ---------------- pad fill: xp = pad(x, 5, value=0.5) ----------------
__global__ void pad_fill_kernel(const float* __restrict__ x, float* __restrict__ xp,
                                int bBase, int gc) {
  size_t total = (size_t)gc * WPD * WPD;
  for (size_t idx = (size_t)blockIdx.x * blockDim.x + threadIdx.x; idx < total;
       idx += (size_t)gridDim.x * blockDim.x) {
    size_t zb = idx / (WPD * WPD);
    int rem = (int)(idx % (WPD * WPD));
    int y = rem / WPD, xx = rem % WPD;
    float v = 0.5f;
    if (y >= 5 && y < 261 && xx >= 5 && xx < 261)
      v = x[((size_t)(bBase + zb) * 256 + (y - 5)) * 256 + (xx - 5)];
    xp[idx] = v;
  }
}

// ---------------- border extrapolation (sequential rings i=5..1) ----------------
__global__ void extrap_kernel(float* __restrict__ xp) {
  const int W = WPD, H = WPD;
  float* p = xp + (size_t)blockIdx.x * W * W;
  for (int i = 5; i >= 1; --i) {
    int ip = i + 1, im = i - 1;
    int L = W - 2 * ip;
    for (int t = threadIdx.x; t < 4 * L; t += blockDim.x) {
      int e = t / L, j = t % L;
      float a;
      if (e == 0) {
        a = (p[i * W + i + j] + p[i * W + i + j + 1] + p[i * W + i + j + 2]) / 3.0f;
        p[im * W + ip + j] = a > 0.3f ? 1.0f : a;
      } else if (e == 1) {
        const float* r = p + (H - ip) * W;
        a = (r[i + j] + r[i + j + 1] + r[i + j + 2]) / 3.0f;
        p[(H - i) * W + ip + j] = a > 0.3f ? 1.0f : a;
      } else if (e == 2) {
        a = (p[(i + j) * W + i] + p[(i + j + 1) * W + i] + p[(i + j + 2) * W + i]) / 3.0f;
        p[(ip + j) * W + im] = a > 0.3f ? 1.0f : a;
      } else {
        a = (p[(i + j) * W + (W - ip)] + p[(i + j + 1) * W + (W - ip)] +
             p[(i + j + 2) * W + (W - ip)]) / 3.0f;
        p[(ip + j) * W + (W - i)] = a > 0.3f ? 1.0f : a;
      }
    }
    __syncthreads();
    if (threadIdx.x < 4) {
      int c = threadIdx.x;
      int cx, cy, nx, ny;
      if (c == 0)      { cx = im;    cy = im;    nx = 1;  ny = 1;  }
      else if (c == 1) { cx = W - i; cy = im;    nx = -1; ny = 1;  }
      else if (c == 2) { cx = W - i; cy = H - i; nx = -1; ny = -1; }
      else             { cx = im;    cy = H - i; nx = 1;  ny = -1; }
      int cxp = cx + nx, cyp = cy + ny;
      p[cy * W + cxp] = (p[cyp * W + cxp] + p[cy * W + cx + 2 * nx]) * 0.5f;
      p[cyp * W + cx] = (p[cyp * W + cxp] + p[(cy + 2 * ny) * W + cx]) * 0.5f;
      p[cy * W + cx]  = (p[cy * W + cxp] + p[cyp * W + cx]) * 0.5f;
    }
    __syncthreads();
  }
}

// ---------------- merged weight repack (w1 | w2 | w3 | w4 in one dispatch) ----
__device__ inline void repack33(const float* W, __hip_bfloat16* Wr, int idx,
                                int CIN, int COUT) {
  int NC = CIN / 32, NF = COUT / 16;
  int j = idx & 7, l = (idx >> 3) & 63;
  int rest = idx >> 9;
  int n = rest % NF; rest /= NF;
  int c = rest % NC; int t = rest / NC;
  int oc = n * 16 + (l & 15);
  int ic = c * 32 + (l >> 4) * 8 + j;
  Wr[idx] = __float2bfloat16(W[((size_t)oc * CIN + ic) * 9 + t]);
}

__global__ void repack_all(const float* __restrict__ W1, const float* __restrict__ W2,
                           const float* __restrict__ W3, const float* __restrict__ W4,
                           __hip_bfloat16* __restrict__ wr) {
  int idx = blockIdx.x * blockDim.x + threadIdx.x;
  if (idx < 2048) {
    int j = idx & 7, l = (idx >> 3) & 63, n = idx >> 9;
    int oc = n * 16 + (l & 15);
    int tap = (l >> 4) * 8 + j;
    wr[idx] = __float2bfloat16(tap < 25 ? W1[oc * 25 + tap] : 0.0f);
  } else if (idx < 20480) {
    repack33(W2, wr + 2048, idx - 2048, 64, 32);
  } else if (idx < 29696) {
    repack33(W3, wr + 20480, idx - 20480, 32, 32);
  } else if (idx < 34304) {
    repack33(W4, wr + 29696, idx - 29696, 32, 16);
  }
}

// involutive bank-spreading swizzle of the 4-chunk index by tile-local x
__device__ inline int swz4(int x) { return (x & 3) ^ ((x >> 2) & 3); }

// ---------------- fused conv1(5x5,1->64)+conv2(3x3,64->32): h1 stays in LDS ----
// XCD-affinity grid permute: blockIdx.x = image (consecutive blocks = different
// images -> round-robin pins each image pair to one XCD; tile walk then reuses
// halo data from that XCD's L2). blockIdx.y/z = tile x/y.
__global__ __launch_bounds__(256, 2)
void conv12_mfma(
    const float* __restrict__ xp, __hip_bfloat16* __restrict__ h2,
    const __hip_bfloat16* __restrict__ w1r, const float* __restrict__ b1,
    const __hip_bfloat16* __restrict__ w2r, const float* __restrict__ b2) {
  const int HIN = WPD;        // xp 266
  const int HO = HO2;         // 260
  const int zb = blockIdx.x;
  const float* p = xp + (size_t)zb * HIN * HIN;
  const int x0 = blockIdx.y * 16, y0 = blockIdx.z * 16;
  const int lane = threadIdx.x & 63;
  const int wave = threadIdx.x >> 6;
  const int lx = lane & 15, kg = lane >> 4;

  __shared__ short lds1[26 * 22];   // rows 0..21 xp data, 22..25 zeros
  __shared__ char lds2[18 * 2304];  // 18x18 x 64ch bf16, CBC=8 chunk-swizzled

  // ---- stage xp patch (f32 -> bf16), zero pad rows ----
  for (int idx = threadIdx.x; idx < 26 * 22; idx += 256) {
    int r = idx / 22, c = idx % 22;
    short v = 0;
    if (r < 22) {
      int yy = min(y0 + r, HIN - 1), xx = min(x0 + c, HIN - 1);
      __hip_bfloat16 h = __float2bfloat16(p[yy * HIN + xx]);
      v = *reinterpret_cast<short*>(&h);
    }
    lds1[idx] = v;
  }

  // conv1 tap offsets (lane-dependent)
  int toff[8]; bool tvalid[8];
#pragma unroll
  for (int j = 0; j < 8; ++j) {
    int tap = kg * 8 + j;
    int ky = tap / 5, kx = tap - ky * 5;
    tvalid[j] = tap < 25;
    toff[j] = ky * 22 + kx;
  }
  // conv2 A-fragment byte bases: pixel x = lx+kx, chunk c = cg*4+kg, slot = c^(x&7)
  int abase[3][2];
#pragma unroll
  for (int kx = 0; kx < 3; ++kx) {
#pragma unroll
    for (int cg = 0; cg < 2; ++cg) {
      int x = lx + kx;
      int c = cg * 4 + kg;
      int slot = c ^ (x & 7);
      abase[kx][cg] = (x * 8 + slot) * 16 + wave * 4 * 2304;
    }
  }

  // conv1 store addresses: pixel = mi*64+wave*16+lx; oc-group n: cb = n*2+(kg>>1)
  int saddr[6][4];
  bool svalid[6];
#pragma unroll
  for (int mi = 0; mi < 6; ++mi) {
    int pixel = mi * 64 + wave * 16 + lx;
    svalid[mi] = pixel < 324;
    int pc = pixel < 324 ? pixel : 323;
    int y2 = pc / 18, x2 = pc - y2 * 18;
#pragma unroll
    for (int n = 0; n < 4; ++n) {
      int cb = n * 2 + (kg >> 1);
      int slot = cb ^ (x2 & 7);
      saddr[mi][n] = y2 * 2304 + (x2 * 8 + slot) * 16 + (kg & 1) * 8;
    }
  }

  __syncthreads();  // lds1 ready

  // ---- hoist conv1 A-fragments: 6 x short8 = 24 VGPR ----
  short8_t Af[6];
#pragma unroll
  for (int mi = 0; mi < 6; ++mi) {
    int pp = mi * 64 + wave * 16 + lx;
    pp = pp < 324 ? pp : 323;
    int y1 = pp / 18, x1 = pp - y1 * 18;
    int bs = y1 * 22 + x1;
#pragma unroll
    for (int j = 0; j < 8; ++j)
      Af[mi][j] = lds1[tvalid[j] ? bs + toff[j] : 484 + lx];
  }

  // ---- conv1: all 64 oc in one pass, swapped-operand MFMA + b64 stores ----
  {
    short8_t B1[4];
    float4_t binit[4];
#pragma unroll
    for (int n = 0; n < 4; ++n) {
      B1[n] = *reinterpret_cast<const short8_t*>(w1r + (size_t)(n * 64 + lane) * 8);
      binit[n] = *reinterpret_cast<const float4_t*>(b1 + n * 16 + kg * 4);
    }
#pragma unroll
    for (int mi = 0; mi < 6; ++mi) {
      if (mi * 64 + wave * 16 < 324) {   // wave-uniform tail skip
        float4_t a[4];
#pragma unroll
        for (int n = 0; n < 4; ++n) {
          a[n] = binit[n];
          a[n] = __builtin_amdgcn_mfma_f32_16x16x32_bf16(B1[n], Af[mi], a[n], 0, 0, 0);
        }
        if (svalid[mi]) {
#pragma unroll
          for (int n = 0; n < 4; ++n) {
            short4_t s;
#pragma unroll
            for (int r = 0; r < 4; ++r) {
              float v = a[n][r] > 0.0f ? a[n][r] : 0.0f;
              __hip_bfloat16 h = __float2bfloat16(v);
              s[r] = *reinterpret_cast<short*>(&h);
            }
            *reinterpret_cast<short4_t*>(lds2 + saddr[mi][n]) = s;
          }
        }
      }
    }
  }
  __syncthreads();  // lds2 (h1, all 64 ch) ready

  // ---- conv2: kx-major with A-row register cache (6 rows per (kx,cg)) ----
  float4_t acc2[4][2];
  {
    float4_t binit2[2];
#pragma unroll
    for (int n = 0; n < 2; ++n)
      binit2[n] = *reinterpret_cast<const float4_t*>(b2 + n * 16 + kg * 4);
#pragma unroll
    for (int m = 0; m < 4; ++m)
#pragma unroll
      for (int n = 0; n < 2; ++n) acc2[m][n] = binit2[n];
  }

#pragma unroll
  for (int kx = 0; kx < 3; ++kx) {
#pragma unroll
    for (int cg = 0; cg < 2; ++cg) {
      short8_t Ar[6];
#pragma unroll
      for (int rr = 0; rr < 6; ++rr)
        Ar[rr] = *reinterpret_cast<const short8_t*>(
            lds2 + abase[kx][cg] + rr * 2304);
#pragma unroll
      for (int ky = 0; ky < 3; ++ky) {
        const int t = ky * 3 + kx;
        short8_t B2[2];
#pragma unroll
        for (int n = 0; n < 2; ++n)
          B2[n] = *reinterpret_cast<const short8_t*>(
              w2r + (size_t)(((t * 2 + cg) * 2 + n) * 64 + lane) * 8);
#pragma unroll
        for (int m = 0; m < 4; ++m)
#pragma unroll
          for (int n = 0; n < 2; ++n)
            acc2[m][n] = __builtin_amdgcn_mfma_f32_16x16x32_bf16(
                B2[n], Ar[m + ky], acc2[m][n], 0, 0, 0);
      }
    }
  }

  // ---- epilogue (swapped layout): pixel = x0+lx, oc = n*16 + kg*4 + r ----
  __hip_bfloat16* op = h2 + (size_t)zb * HO * HO * 32;
  int xx = x0 + lx;
  if (xx < HO) {
#pragma unroll
    for (int m = 0; m < 4; ++m) {
      int yy = y0 + wave * 4 + m;
      if (yy < HO) {
#pragma unroll
        for (int n = 0; n < 2; ++n) {
          short4_t s;
#pragma unroll
          for (int r = 0; r < 4; ++r) {
            float v = acc2[m][n][r];
            v = v > 0.0f ? v : 0.0f;
            __hip_bfloat16 h = __float2bfloat16(v);
            s[r] = *reinterpret_cast<short*>(&h);
          }
          *reinterpret_cast<short4_t*>(op + ((size_t)yy * HO + xx) * 32 + n * 16 + kg * 4) = s;
        }
      }
    }
  }
}

// ---------------- fused conv3(3x3,32->32)+conv4(3x3,32->16)+sigmoid+shuffle ----
// R16 (best-measured) mi-outer conv3; XCD-affinity grid permute (image on x).
__global__ __launch_bounds__(256, 2)
void conv34_mfma(
    const __hip_bfloat16* __restrict__ h2, float* __restrict__ out,
    const __hip_bfloat16* __restrict__ w3r, const float* __restrict__ b3,
    const __hip_bfloat16* __restrict__ w4r, const float* __restrict__ b4,
    int bBase) {
  const int HIN = HO2;   // 260
  const int zb = blockIdx.x;
  const __hip_bfloat16* ip = h2 + (size_t)zb * HIN * HIN * 32;
  const int x0 = blockIdx.y * 16, y0 = blockIdx.z * 16;
  const int lane = threadIdx.x & 63;
  const int wave = threadIdx.x >> 6;
  const int lx = lane & 15, kg = lane >> 4;

  constexpr int SLOTS = 20 * 20 * 4;            // 1600
  constexpr int ITERS = (SLOTS + 255) / 256;    // 7
  __shared__ char lds1[ITERS * 256 * 16];       // 28672 B: 20x20x32 h2 tile
  __shared__ char lds2[18 * 1152];              // 20736 B: 18x18x32 h3 tile

  // ---- stage h2 tile (swizzled global source, linear LDS dest) ----
#pragma unroll
  for (int i = 0; i < ITERS; ++i) {
    int sbase = i * 256 + wave * 64;            // wave-uniform
    int slot = sbase + lane;
    slot = slot < SLOTS ? slot : SLOTS - 1;
    int pix = slot >> 2, scb = slot & 3;
    int y = pix / 20, x = pix - y * 20;
    int cb = scb ^ swz4(x);
    const __hip_bfloat16* src = ip + ((size_t)(y0 + y) * HIN + (x0 + x)) * 32 + cb * 8;
    gld16(src, lds1 + (size_t)sbase * 16);
  }

  // conv4 fragment byte bases (per kx) into lds2
  int abase4[3];
#pragma unroll
  for (int kx = 0; kx < 3; ++kx) {
    int x = lx + kx;
    int slot = kg ^ swz4(x);
    abase4[kx] = (x * 4 + slot) * 16 + wave * 4 * 1152;
  }

  // conv3 per-mi addresses (pixel-linearized over 18x18 h3 tile)
  int a3base[6];
  int s3[6][3];
  int saddr[6][2];
  bool svalid[6];
#pragma unroll
  for (int mi = 0; mi < 6; ++mi) {
    int pixel = mi * 64 + wave * 16 + lx;
    svalid[mi] = pixel < 324;
    int pc = pixel < 324 ? pixel : 323;
    int y1 = pc / 18, x1 = pc - y1 * 18;
    a3base[mi] = (y1 * 20 + x1) * 64;
#pragma unroll
    for (int kx = 0; kx < 3; ++kx) s3[mi][kx] = kg ^ swz4(x1 + kx);
#pragma unroll
    for (int n2 = 0; n2 < 2; ++n2) {
      int cb = n2 * 2 + (kg >> 1);
      int slot = cb ^ swz4(x1);
      saddr[mi][n2] = y1 * 1152 + (x1 * 4 + slot) * 16 + (kg & 1) * 8;
    }
  }

  float4_t binit3[2];
#pragma unroll
  for (int n2 = 0; n2 < 2; ++n2)
    binit3[n2] = *reinterpret_cast<const float4_t*>(b3 + n2 * 16 + kg * 4);

  __syncthreads();  // lds1 ready

  // ---- conv3: swapped-operand MFMA over 9 taps, store h3 into lds2 ----
#pragma unroll
  for (int mi = 0; mi < 6; ++mi) {
    if (mi * 64 + wave * 16 < 324) {
      float4_t a0 = binit3[0];
      float4_t a1 = binit3[1];
#pragma unroll
      for (int t = 0; t < 9; ++t) {
        const int ky = t / 3, kx = t % 3;
        short8_t B30 = *reinterpret_cast<const short8_t*>(
            w3r + (size_t)((t * 2 + 0) * 64 + lane) * 8);
        short8_t B31 = *reinterpret_cast<const short8_t*>(
            w3r + (size_t)((t * 2 + 1) * 64 + lane) * 8);
        short8_t A = *reinterpret_cast<const short8_t*>(
            lds1 + a3base[mi] + ky * 1280 + kx * 64 + s3[mi][kx] * 16);
        a0 = __builtin_amdgcn_mfma_f32_16x16x32_bf16(B30, A, a0, 0, 0, 0);
        a1 = __builtin_amdgcn_mfma_f32_16x16x32_bf16(B31, A, a1, 0, 0, 0);
      }
      if (svalid[mi]) {
        short4_t s0, s1;
#pragma unroll
        for (int r = 0; r < 4; ++r) {
          float v0 = a0[r] > 0.0f ? a0[r] : 0.0f;
          float v1 = a1[r] > 0.0f ? a1[r] : 0.0f;
          __hip_bfloat16 h0 = __float2bfloat16(v0);
          __hip_bfloat16 h1 = __float2bfloat16(v1);
          s0[r] = *reinterpret_cast<short*>(&h0);
          s1[r] = *reinterpret_cast<short*>(&h1);
        }
        *reinterpret_cast<short4_t*>(lds2 + saddr[mi][0]) = s0;
        *reinterpret_cast<short4_t*>(lds2 + saddr[mi][1]) = s1;
      }
    }
  }
  __syncthreads();  // lds2 (h3) ready

  // ---- conv4: kx-major with A-row register cache (6 rows per kx) ----
  float4_t binit4 = *reinterpret_cast<const float4_t*>(b4 + kg * 4);
  float4_t acc[4];
#pragma unroll
  for (int m = 0; m < 4; ++m) acc[m] = binit4;

#pragma unroll
  for (int kx = 0; kx < 3; ++kx) {
    short8_t Ar[6];
#pragma unroll
    for (int rr = 0; rr < 6; ++rr)
      Ar[rr] = *reinterpret_cast<const short8_t*>(lds2 + abase4[kx] + rr * 1152);
#pragma unroll
    for (int ky = 0; ky < 3; ++ky) {
      const int t = ky * 3 + kx;
      short8_t B = *reinterpret_cast<const short8_t*>(w4r + (size_t)(t * 64 + lane) * 8);
#pragma unroll
      for (int m = 0; m < 4; ++m)
        acc[m] = __builtin_amdgcn_mfma_f32_16x16x32_bf16(B, Ar[m + ky], acc[m], 0, 0, 0);
    }
  }

  // ---- sigmoid + pixel_shuffle (swapped): pixel = x0+lx, oc = kg*4+r ----
  float* ob = out + (size_t)(bBase + zb) * 1024 * 1024;
  int xx = x0 + lx;
#pragma unroll
  for (int m = 0; m < 4; ++m) {
    int yy = y0 + wave * 4 + m;
    float4_t v;
#pragma unroll
    for (int r = 0; r < 4; ++r) v[r] = 1.0f / (1.0f + expf(-acc[m][r]));
    *reinterpret_cast<float4_t*>(ob + (size_t)(yy * 4 + kg) * 1024 + xx * 4) = v;
  }
}

extern "C" void kernel_launch(void* const* d_in, const int* in_sizes, int n_in,
                              void* d_out, int out_size, void* d_ws, size_t ws_size,
                              hipStream_t stream) {
  const float* x  = (const float*)d_in[0];
  const float* W1 = (const float*)d_in[1];
  const float* b1 = (const float*)d_in[2];
  const float* W2 = (const float*)d_in[3];
  const float* b2 = (const float*)d_in[4];
  const float* W3 = (const float*)d_in[5];
  const float* b3 = (const float*)d_in[6];
  const float* W4 = (const float*)d_in[7];
  const float* b4 = (const float*)d_in[8];
  float* out = (float*)d_out;

  __hip_bfloat16* wr = (__hip_bfloat16*)d_ws;
  __hip_bfloat16* wr1 = wr;               // 2048 elems
  __hip_bfloat16* wr2 = wr + 2048;        // 18432
  __hip_bfloat16* wr3 = wr + 20480;       // 9216
  __hip_bfloat16* wr4 = wr + 29696;       // 4608 (total 34304)
  char* base = (char*)d_ws + 131072;

  const size_t xp_sz = (size_t)WPD * WPD * sizeof(float);
  const size_t h2_sz = (size_t)HO2 * HO2 * 32 * sizeof(__hip_bfloat16);
  const size_t per_b = xp_sz + h2_sz;     // ~4.6 MB/batch

  int g = (int)((ws_size - 131072) / per_b);
  if (g > 16) g = 16;
  if (g < 1) g = 1;

  float* xp = (float*)base;
  __hip_bfloat16* h2 = (__hip_bfloat16*)(base + (size_t)g * xp_sz);

  repack_all<<<134, 256, 0, stream>>>(W1, W2, W3, W4, wr);

  for (int bBase = 0; bBase < 16; bBase += g) {
    int gc = min(g, 16 - bBase);
    size_t tot = (size_t)gc * WPD * WPD;
    int fillBlocks = (int)min((tot + 255) / 256, (size_t)2048);
    pad_fill_kernel<<<fillBlocks, 256, 0, stream>>>(x, xp, bBase, gc);
    extrap_kernel<<<gc, 256, 0, stream>>>(xp);
    // image on blockIdx.x -> XCD affinity; tiles on y/z
    conv12_mfma<<<dim3(gc, 17, 17), 256, 0, stream>>>(xp, h2, wr1, b1, wr2, b2);
    conv34_mfma<<<dim3(gc, 16, 16), 256, 0, stream>>>(h2, out, wr3, b3, wr4, b4, bBase);
  }
}